// Round 16
// baseline (96.614 us; speedup 1.0000x reference)
//
#include <hip/hip_runtime.h>

// Head attention forward: x[4,4096,1024] f32, Wk/Wq/Wv [1024,128] f32 -> out[4,4096,128] f32
// Pipeline: (1) W transpose->bf16, (2) FUSED QKV projection: x read ONCE
// (64-row tile x all 384 output cols, 8 waves, A/B reg-prefetched one kt ahead;
// q pre-scaled by C^-0.5, v stored PRE-TILED vTc[keyblk][128 d][64 key]),
// (3) split-KV flash attention (R14-verified): 8 waves x 16 q-rows share
// LDS-staged K+V (dbuf global_load_lds, pre-swizzled source), swapped QK^T,
// in-lane softmax with gated defer-max, lane-local l_, XCD chunk-affinity
// remap (FETCH 32->13MB verified); phase 2 = merge.

typedef __bf16 bf16;
typedef bf16 bf16x8 __attribute__((ext_vector_type(8)));
typedef bf16 bf16x4 __attribute__((ext_vector_type(4)));
typedef float f32x4 __attribute__((ext_vector_type(4)));

#define L2E 1.4426950408889634f
#define TSEQ 4096
#define CDIM 1024
#define HDIM 128
#define MROWS 16384  // B*T

// async global->LDS, 16B per lane; LDS dest = wave-uniform base + lane*16
#define GLDS(g, l)                                              \
  __builtin_amdgcn_global_load_lds(                             \
      (__attribute__((address_space(1))) void*)(g),             \
      (__attribute__((address_space(3))) void*)(l), 16, 0, 0)

// pack two floats into one dword of bf16 (lo = a, hi = b)
static __device__ inline unsigned pkbf(float a, float b) {
  union { bf16 h; unsigned short u; } ua, ub;
  ua.h = (bf16)a; ub.h = (bf16)b;
  return ((unsigned)ub.u << 16) | (unsigned)ua.u;
}

// ---------------------------------------------------------------------------
// prep: W [1024][128] f32 (in,out)  ->  WT [128][1024] bf16  (out-major)
// ---------------------------------------------------------------------------
__global__ __launch_bounds__(256) void wt_prep(const float* __restrict__ Wq,
                                               const float* __restrict__ Wk,
                                               const float* __restrict__ Wv,
                                               bf16* __restrict__ WT) {
  const int mode = blockIdx.y;
  const float* W = (mode == 0) ? Wq : (mode == 1) ? Wk : Wv;
  const int idx = blockIdx.x * 256 + threadIdx.x;  // 0..131071 over [128][1024]
  const int n = idx >> 10;                         // head dim 0..127
  const int k = idx & 1023;                        // in dim  0..1023
  WT[(size_t)mode * 131072 + idx] = (bf16)W[(size_t)k * HDIM + n];
}

// ---------------------------------------------------------------------------
// FUSED QKV GEMM: [q|k|v](16384, 3x128) = x(16384,1024) @ [Wq|Wk|Wv] — x read ONCE.
// 256 blocks x 512 thr (= 1 block/CU); tile 64 rows x 384 cols; 8 waves (2x4),
// each 32 rows x 96 cols (12 acc frags). A staged f32->bf16 and B (all 3 modes)
// staged from WT, BOTH reg-prefetched one kt ahead (R10-verified schedule; no
// mid-loop GLDS -> no barrier-drain stall, R8/R13's failure mode). LDS 28 KB.
// mode 0: qb scaled 1/32; mode 1: kb; mode 2: vTc[key>>6][d][key&63] pre-tiled.
// ---------------------------------------------------------------------------
__global__ __launch_bounds__(512, 2) void qkv_fused(const float* __restrict__ x,
                                                    const bf16* __restrict__ WT,
                                                    bf16* __restrict__ qb,
                                                    bf16* __restrict__ kb,
                                                    bf16* __restrict__ vT) {
  __shared__ __attribute__((aligned(16))) bf16 a_tile[64 * 32];    //  4 KB
  __shared__ __attribute__((aligned(16))) bf16 b_tile[384 * 32];   // 24 KB
  const int tid = threadIdx.x;
  const int wid = tid >> 6;       // 0..7
  const int lane = tid & 63;
  const int lr = lane & 15;
  const int lg = lane >> 4;
  const int wr = wid >> 2;        // 0..1: 32-row half
  const int wcg = wid & 3;        // 0..3: 96-col group
  const int m0 = blockIdx.x * 64;

  // A staging: thread -> row ra = tid>>3, 4 f32 at col (tid&7)*4
  const int ra = tid >> 3;
  const int ca = (tid & 7) * 4;
  // B staging: fB[i] (i == mode), row-within-mode rb = tid>>2, col8 = (tid&3)*8
  const int rb = tid >> 2;        // 0..127
  const int cb = (tid & 3) * 8;

  f32x4 acc[2][6] = {};
  float4 a0;
  bf16x8 fB[3];
  {  // prefetch kt = 0
    a0 = *(const float4*)(x + (size_t)(m0 + ra) * CDIM + ca);
#pragma unroll
    for (int i = 0; i < 3; ++i)
      fB[i] = *(const bf16x8*)(WT + (size_t)i * 131072 + rb * 1024 + cb);
  }

#pragma unroll 1
  for (int kt = 0; kt < 32; ++kt) {
    __syncthreads();  // prior iteration's fragment reads done
    {
      bf16x4 av;
      av[0] = (bf16)a0.x; av[1] = (bf16)a0.y; av[2] = (bf16)a0.z; av[3] = (bf16)a0.w;
      *(bf16x4*)&a_tile[ra * 32 + ca] = av;
#pragma unroll
      for (int i = 0; i < 3; ++i)
        *(bf16x8*)&b_tile[(i * 128 + rb) * 32 + cb] = fB[i];
    }
    __syncthreads();  // tiles staged
    if (kt + 1 < 32) {  // prefetch next kt (flies under compute)
      a0 = *(const float4*)(x + (size_t)(m0 + ra) * CDIM + (kt + 1) * 32 + ca);
#pragma unroll
      for (int i = 0; i < 3; ++i)
        fB[i] = *(const bf16x8*)(WT + (size_t)i * 131072 + rb * 1024 + (kt + 1) * 32 + cb);
    }
    bf16x8 af[2];
#pragma unroll
    for (int r = 0; r < 2; ++r)
      af[r] = *(const bf16x8*)&a_tile[(wr * 32 + r * 16 + lr) * 32 + lg * 8];
#pragma unroll
    for (int n = 0; n < 6; ++n) {
      bf16x8 bfr = *(const bf16x8*)&b_tile[(wcg * 96 + n * 16 + lr) * 32 + lg * 8];
      acc[0][n] = __builtin_amdgcn_mfma_f32_16x16x32_bf16(af[0], bfr, acc[0][n], 0, 0, 0);
      acc[1][n] = __builtin_amdgcn_mfma_f32_16x16x32_bf16(af[1], bfr, acc[1][n], 0, 0, 0);
    }
  }

  // epilogue: frag (r,n): rows m0+32wr+16r+lg*4+j; packed col cg = 96wcg+16n
#pragma unroll
  for (int r = 0; r < 2; ++r) {
    const int row0 = m0 + wr * 32 + r * 16 + lg * 4;
#pragma unroll
    for (int n = 0; n < 6; ++n) {
      const int cg = wcg * 96 + n * 16;  // 0..383, wave-uniform
      const int mode = cg >> 7;          // 0=q, 1=k, 2=v
      const int col = (cg & 127) + lr;
      if (mode < 2) {
        bf16* dst = (mode == 0) ? qb : kb;
        const float sc = (mode == 0) ? 0.03125f : 1.0f;  // fold C^-0.5 into q
#pragma unroll
        for (int j = 0; j < 4; ++j)
          dst[(size_t)(row0 + j) * HDIM + col] = (bf16)(acc[r][n][j] * sc);
      } else {
        bf16x4 pv;
        pv[0] = (bf16)acc[r][n][0]; pv[1] = (bf16)acc[r][n][1];
        pv[2] = (bf16)acc[r][n][2]; pv[3] = (bf16)acc[r][n][3];
        *(bf16x4*)(vT + (size_t)(row0 >> 6) * 8192 + col * 64 + (row0 & 63)) = pv;
      }
    }
  }
}

// ---------------------------------------------------------------------------
// Flash attention phase 1 (split-KV, block-cooperative, swapped QK^T) — R14
// verified. Block = 8 waves x 16 q-rows = 128 rows over one KV chunk. K tile
// (64x128) and V tile (128x64, pre-tiled vTc) staged in LDS, dbuf, via
// global_load_lds with pre-swizzled source (col ^= (row&7)<<4). S^T = mfma(K,Q):
// softmax in-lane; gated defer-max; lane-local l_. 80 KB LDS -> 2 blocks/CU.
// XCD chunk-affinity (maxc==8): XCD j runs chunks {(c=j,b=0,1),(c=7-j,b=2,3)}.
// ---------------------------------------------------------------------------
__global__ __launch_bounds__(512, 4) void attn_part(const bf16* __restrict__ qg,
                                                    const bf16* __restrict__ kb,
                                                    const bf16* __restrict__ vT,
                                                    bf16* __restrict__ po,
                                                    float* __restrict__ pm,
                                                    float* __restrict__ pl,
                                                    int cshift, int maxc) {
  // [2 buffers][K 16KB | V 16KB] + P 16KB = 80 KB
  __shared__ __attribute__((aligned(16))) char kv_lds[2][32768];
  __shared__ __attribute__((aligned(16))) bf16 p_lds[8][16][64];
  const int tid = threadIdx.x;
  const int wid = tid >> 6;       // 0..7
  const int lane = tid & 63;
  const int lr = lane & 15;
  const int lg = lane >> 4;

  // ---- XCD chunk-affinity remap (maxc==8 tier only) ----
  int bx = blockIdx.x, c = blockIdx.y, b = blockIdx.z;
  if (maxc == 8) {
    const int p = blockIdx.x + 32 * (blockIdx.y + 8 * blockIdx.z);
    const int xcd = p & 7;
    const int s = p >> 3;        // 0..127 within XCD
    const int combo = s >> 5;    // 0..3
    bx = s & 31;
    b = combo;
    c = (combo < 2) ? xcd : 7 - xcd;
  }

  const int qbase = bx * 128;
  const int kv0 = c << cshift;
  if (kv0 >= qbase + 128) return;  // block-uniform early exit
  const int kvend = min(kv0 + (1 << cshift), qbase + 128);  // 64-multiples
  const int nt = (kvend - kv0) >> 6;
  const int qr0 = qbase + wid * 16;
  const int grp = bx * 8 + wid;  // 0..255
  const size_t qrow = (size_t)b * TSEQ + qr0;

  // ---- staging source byte offsets (source pre-swizzled, dest linear) ----
  const int wbase = wid * 2048;  // each wave stages 2KB of K and 2KB of V
  int ksrc[2], vsrc[2];
#pragma unroll
  for (int i = 0; i < 2; ++i) {
    const int o = wbase + i * 1024 + lane * 16;  // linear dest byte in tile
    const int rk = o >> 8;                       // K row (256B rows)
    ksrc[i] = rk * 256 + ((o & 255) ^ ((rk & 7) << 4));
    const int rv = o >> 7;                       // V d-row (128B rows, contiguous tile)
    vsrc[i] = rv * 128 + ((o & 127) ^ ((rv & 7) << 4));
  }
  const char* kgb = (const char*)kb + (size_t)b * TSEQ * 256;  // + key*256B
  const char* vgb = (const char*)vT + (size_t)b * TSEQ * 256;  // + key*256B (tiled)

  // ---- fragment read bases (XOR split over disjoint bit fields) ----
  const int msk = (lr & 7) << 4;  // full mask bits 4-6
  const int m30 = (lr & 3) << 4;  // mask bits 4-5
  const int m6 = (lr & 4) << 4;   // mask bit 6
  const int lgx = (lg * 16) ^ m30;
  const int kreadA = lr * 256 + lgx + m6;         // d even (+128 for d=2)
  const int kreadB = lr * 256 + lgx + (64 ^ m6);  // d odd  (+128 for d=3)
  const int vreadA = 16384 + lr * 128 + lgx + m6;         // ks=0
  const int vreadB = 16384 + lr * 128 + lgx + (64 ^ m6);  // ks=1

  // Q fragments (hoisted): B-operand layout
  bf16x8 qf[4];
#pragma unroll
  for (int d = 0; d < 4; ++d)
    qf[d] = *(const bf16x8*)(qg + (qrow + lr) * HDIM + d * 32 + lg * 8);

  f32x4 o_[8] = {};              // O^T: o_[o][j] = O[q=lr][d = 16o + 4lg + j]
  float m_ = -1e30f, l_ = 0.0f;  // m_: row-uniform running max; l_: LANE-LOCAL

  // ---- prologue: stage tile 0 into buffer 0 ----
  {
    const char* ks = kgb + (size_t)kv0 * 256;
    const char* vs = vgb + (size_t)kv0 * 256;
#pragma unroll
    for (int i = 0; i < 2; ++i) {
      GLDS(ks + ksrc[i], &kv_lds[0][wbase + i * 1024]);
      GLDS(vs + vsrc[i], &kv_lds[0][16384 + wbase + i * 1024]);
    }
  }
  __syncthreads();  // drains vmcnt: tile 0 resident

  int cur = 0;
  for (int t = 0; t < nt; ++t) {
    const int kvt = kv0 + (t << 6);
    // ---- issue next tile's staging (flies under compute) ----
    if (t + 1 < nt) {
      const char* ks = kgb + (size_t)(kvt + 64) * 256;
      const char* vs = vgb + (size_t)(kvt + 64) * 256;
#pragma unroll
      for (int i = 0; i < 2; ++i) {
        GLDS(ks + ksrc[i], &kv_lds[cur ^ 1][wbase + i * 1024]);
        GLDS(vs + vsrc[i], &kv_lds[cur ^ 1][16384 + wbase + i * 1024]);
      }
    }
    // ---- compute (waves whose rows end before this tile just barrier) ----
    if (kvt < qr0 + 16) {
      const char* kbuf = kv_lds[cur];
      // S^T = mfma(A=K, B=Q): s[nf][j] = S[q=lr][key = kvt + nf*16 + lg*4 + j]
      f32x4 s[4] = {};
      __builtin_amdgcn_s_setprio(1);
#pragma unroll
      for (int nf = 0; nf < 4; ++nf) {
        const char* kb0 = kbuf + nf * 4096;
        bf16x8 kf;
        kf = *(const bf16x8*)(kb0 + kreadA);
        s[nf] = __builtin_amdgcn_mfma_f32_16x16x32_bf16(kf, qf[0], s[nf], 0, 0, 0);
        kf = *(const bf16x8*)(kb0 + kreadB);
        s[nf] = __builtin_amdgcn_mfma_f32_16x16x32_bf16(kf, qf[1], s[nf], 0, 0, 0);
        kf = *(const bf16x8*)(kb0 + kreadA + 128);
        s[nf] = __builtin_amdgcn_mfma_f32_16x16x32_bf16(kf, qf[2], s[nf], 0, 0, 0);
        kf = *(const bf16x8*)(kb0 + kreadB + 128);
        s[nf] = __builtin_amdgcn_mfma_f32_16x16x32_bf16(kf, qf[3], s[nf], 0, 0, 0);
      }
      __builtin_amdgcn_s_setprio(0);
      // causal mask (only tiles crossing the diagonal)
      if (kvt + 63 >= qr0) {
        const int q = qr0 + lr;
#pragma unroll
        for (int nf = 0; nf < 4; ++nf)
#pragma unroll
          for (int j = 0; j < 4; ++j)
            if (kvt + nf * 16 + lg * 4 + j > q) s[nf][j] = -1e30f;
      }
      // lane-local row max over this lane's 16 scores
      float rloc = fmaxf(fmaxf(s[0][0], s[0][1]), fmaxf(s[0][2], s[0][3]));
#pragma unroll
      for (int nf = 1; nf < 4; ++nf)
        rloc = fmaxf(rloc, fmaxf(fmaxf(s[nf][0], s[nf][1]), fmaxf(s[nf][2], s[nf][3])));
      // gated defer-max: cross-lane reduce + rescale only when needed
      if (!__all(rloc <= m_ + 8.0f)) {
        float rmax = fmaxf(rloc, __shfl_xor(rloc, 16));
        rmax = fmaxf(rmax, __shfl_xor(rmax, 32));
        const float mn = fmaxf(m_, rmax);
        const float al = exp2f((m_ - mn) * L2E);
        m_ = mn;
        l_ *= al;
#pragma unroll
        for (int o = 0; o < 8; ++o)
#pragma unroll
          for (int j = 0; j < 4; ++j) o_[o][j] *= al;
      }
      float rsum = 0.0f;
#pragma unroll
      for (int nf = 0; nf < 4; ++nf)
#pragma unroll
        for (int j = 0; j < 4; ++j) {
          s[nf][j] = exp2f((s[nf][j] - m_) * L2E);
          rsum += s[nf][j];
        }
      l_ += rsum;  // lane-local; cross-lane reduced once at the end
      // P^T -> swizzled p_lds [q-row][key], one b64 write per nf
      {
        char* pw = (char*)p_lds + wid * 2048 + lr * 128;
#pragma unroll
        for (int nf = 0; nf < 4; ++nf) {
          uint2 w2;
          w2.x = pkbf(s[nf][0], s[nf][1]); w2.y = pkbf(s[nf][2], s[nf][3]);
          *(uint2*)(pw + (((nf * 32) + lg * 8) ^ msk)) = w2;
        }
      }
      asm volatile("s_waitcnt lgkmcnt(0)" ::: "memory");
      __builtin_amdgcn_sched_barrier(0);  // keep dependent MFMAs below the wait
      // O^T += V^T P^T  (A = V^T frag; B = P^T frag, swizzled read)
      const char* pr = (const char*)p_lds + wid * 2048 + lr * 128;
      bf16x8 pf0 = *(const bf16x8*)(pr + lgx + m6);
      bf16x8 pf1 = *(const bf16x8*)(pr + lgx + (64 ^ m6));
      __builtin_amdgcn_s_setprio(1);
#pragma unroll
      for (int o = 0; o < 8; ++o) {
        bf16x8 vf;
        vf = *(const bf16x8*)(kbuf + vreadA + o * 2048);
        o_[o] = __builtin_amdgcn_mfma_f32_16x16x32_bf16(vf, pf0, o_[o], 0, 0, 0);
        vf = *(const bf16x8*)(kbuf + vreadB + o * 2048);
        o_[o] = __builtin_amdgcn_mfma_f32_16x16x32_bf16(vf, pf1, o_[o], 0, 0, 0);
      }
      __builtin_amdgcn_s_setprio(0);
    }
    __syncthreads();  // staging (vmcnt) drained; everyone done with buf[cur]
    cur ^= 1;
  }

  // ---- finalize lane-local l_ (one cross-lane reduce per kernel) ----
  l_ += __shfl_xor(l_, 16);
  l_ += __shfl_xor(l_, 32);

  // ---- write unnormalized partials: lane owns q-row lr ----
  const size_t slot = (size_t)(b * 256 + grp) * maxc + c;
  bf16* pob = po + slot * (16 * HDIM);
#pragma unroll
  for (int o = 0; o < 8; ++o) {
    bf16x4 pv;
    pv[0] = (bf16)o_[o][0]; pv[1] = (bf16)o_[o][1];
    pv[2] = (bf16)o_[o][2]; pv[3] = (bf16)o_[o][3];
    *(bf16x4*)(pob + lr * HDIM + o * 16 + lg * 4) = pv;
  }
  if (lg == 0) {
    pm[slot * 16 + lr] = m_;
    pl[slot * 16 + lr] = l_;
  }
}

// ---------------------------------------------------------------------------
// Flash attention phase 2: merge <=maxc partials per (batch, group).
// ---------------------------------------------------------------------------
__global__ __launch_bounds__(256) void attn_merge(const bf16* __restrict__ po,
                                                  const float* __restrict__ pm,
                                                  const float* __restrict__ pl,
                                                  float* __restrict__ out,
                                                  int cshift, int maxc) {
  const int bg = blockIdx.x;          // b*256 + g
  const int g = bg & 255;
  const int nch = ((g << 4) >> cshift) + 1;
  const int row = threadIdx.x >> 4;
  const int d8 = (threadIdx.x & 15) * 8;
  const size_t slot0 = (size_t)bg * maxc;

  float M = -1e30f;
  for (int c = 0; c < nch; ++c) M = fmaxf(M, pm[(slot0 + c) * 16 + row]);
  float L = 0.0f;
  float acc[8] = {};
  for (int c = 0; c < nch; ++c) {
    const float w = exp2f((pm[(slot0 + c) * 16 + row] - M) * L2E);
    L += w * pl[(slot0 + c) * 16 + row];
    const bf16x8 v = *(const bf16x8*)(po + (slot0 + c) * (16 * HDIM) + row * HDIM + d8);
#pragma unroll
    for (int i = 0; i < 8; ++i) acc[i] += w * (float)v[i];
  }
  const float inv = 1.0f / L;
  f32x4 r0, r1;
#pragma unroll
  for (int i = 0; i < 4; ++i) { r0[i] = acc[i] * inv; r1[i] = acc[i + 4] * inv; }
  float* dst = out + (size_t)bg * (16 * HDIM) + row * HDIM + d8;
  *(f32x4*)dst = r0;
  *(f32x4*)(dst + 4) = r1;
}

// ---------------------------------------------------------------------------
extern "C" void kernel_launch(void* const* d_in, const int* in_sizes, int n_in,
                              void* d_out, int out_size, void* d_ws, size_t ws_size,
                              hipStream_t stream) {
  const float* x  = (const float*)d_in[0];
  const float* Wk = (const float*)d_in[1];
  const float* Wq = (const float*)d_in[2];
  const float* Wv = (const float*)d_in[3];
  float* out = (float*)d_out;

  char* ws = (char*)d_ws;
  bf16* qb = (bf16*)(ws);                   // [16384][128] bf16, 4 MB
  bf16* kb = (bf16*)(ws + 4194304);         // [16384][128] bf16, 4 MB
  bf16* vT = (bf16*)(ws + 8388608);         // vTc[256][128][64] bf16, 4 MB
  bf16* WT = (bf16*)(ws + 12582912);        // [3][128][1024] bf16, 768 KB
  const size_t pbase = 13369344;

  // choose KV-chunking tier by available workspace:
  //   per-slot bytes: 16*128*2 (po) + 2*16*4 (pm,pl) = 4224; slots = 1024*maxc
  int cshift, maxc;
  if (ws_size >= pbase + 8ull * 1024 * 4224) { cshift = 9;  maxc = 8; }       // 512-key chunks
  else if (ws_size >= pbase + 4ull * 1024 * 4224) { cshift = 10; maxc = 4; }  // 1024-key
  else { cshift = 12; maxc = 1; }                                             // no split
  bf16* po = (bf16*)(ws + pbase);
  float* pm = (float*)(ws + pbase + (size_t)maxc * 1024 * 16 * 128 * 2);
  float* pl = pm + (size_t)maxc * 1024 * 16;

  wt_prep<<<dim3(512, 3), 256, 0, stream>>>(Wq, Wk, Wv, WT);
  qkv_fused<<<256, 512, 0, stream>>>(x, WT, qb, kb, vT);
  attn_part<<<dim3(32, maxc, 4), 512, 0, stream>>>(qb, kb, vT, po, pm, pl, cshift, maxc);
  attn_merge<<<1024, 256, 0, stream>>>(po, pm, pl, out, cshift, maxc);
}

// Round 17
// 90.882 us; speedup vs baseline: 1.0631x; 1.0631x over previous
//
#include <hip/hip_runtime.h>

// Head attention forward: x[4,4096,1024] f32, Wk/Wq/Wv [1024,128] f32 -> out[4,4096,128] f32
// Pipeline: (1) W transpose->bf16, (2) QKV projection via bf16 MFMA GEMM (3 modes,
// XCD mode-affinity remap: the 3 mode-blocks of each row-tile run adjacently on one
// XCD so x re-reads hit L2; q pre-scaled by C^-0.5, v stored PRE-TILED
// vTc[keyblk][128 d][64 key]; A/B reg-prefetched one kt ahead), (3) split-KV flash
// attention (R14-verified): 8 waves x 16 q-rows share LDS-staged K+V (dbuf
// global_load_lds, pre-swizzled source), swapped QK^T, in-lane softmax with gated
// defer-max, lane-local l_, XCD chunk-affinity remap (FETCH 32->13MB verified);
// phase 2 = merge.

typedef __bf16 bf16;
typedef bf16 bf16x8 __attribute__((ext_vector_type(8)));
typedef bf16 bf16x4 __attribute__((ext_vector_type(4)));
typedef float f32x4 __attribute__((ext_vector_type(4)));

#define L2E 1.4426950408889634f
#define TSEQ 4096
#define CDIM 1024
#define HDIM 128
#define MROWS 16384  // B*T

// async global->LDS, 16B per lane; LDS dest = wave-uniform base + lane*16
#define GLDS(g, l)                                              \
  __builtin_amdgcn_global_load_lds(                             \
      (__attribute__((address_space(1))) void*)(g),             \
      (__attribute__((address_space(3))) void*)(l), 16, 0, 0)

// pack two floats into one dword of bf16 (lo = a, hi = b)
static __device__ inline unsigned pkbf(float a, float b) {
  union { bf16 h; unsigned short u; } ua, ub;
  ua.h = (bf16)a; ub.h = (bf16)b;
  return ((unsigned)ub.u << 16) | (unsigned)ua.u;
}

// ---------------------------------------------------------------------------
// prep: W [1024][128] f32 (in,out)  ->  WT [128][1024] bf16  (out-major)
// ---------------------------------------------------------------------------
__global__ __launch_bounds__(256) void wt_prep(const float* __restrict__ Wq,
                                               const float* __restrict__ Wk,
                                               const float* __restrict__ Wv,
                                               bf16* __restrict__ WT) {
  const int mode = blockIdx.y;
  const float* W = (mode == 0) ? Wq : (mode == 1) ? Wk : Wv;
  const int idx = blockIdx.x * 256 + threadIdx.x;  // 0..131071 over [128][1024]
  const int n = idx >> 10;                         // head dim 0..127
  const int k = idx & 1023;                        // in dim  0..1023
  WT[(size_t)mode * 131072 + idx] = (bf16)W[(size_t)k * HDIM + n];
}

// ---------------------------------------------------------------------------
// QKV GEMM (R10-verified schedule + XCD mode-affinity): C = x @ W per mode.
// 128x128 tile, BK=32, 4 waves (2x2 of 64x64), mfma_f32_16x16x32_bf16.
// A and B reg-prefetched one K-step ahead. Block remap: p=bx+128*by ->
// xcd=p&7, s=p>>3; tile = xcd*16 + s/3, mode = s%3 — the 3 mode-blocks of a
// tile are adjacent on ONE XCD, so modes 1/2 re-read x from L2 (not L3/HBM).
// mode 0: qb scaled 1/32; mode 1: kb; mode 2: vTc[key>>6][d][key&63] pre-tiled.
// ---------------------------------------------------------------------------
__global__ __launch_bounds__(256) void qkv_gemm(const float* __restrict__ x,
                                                const bf16* __restrict__ WT,
                                                bf16* __restrict__ qb,
                                                bf16* __restrict__ kb,
                                                bf16* __restrict__ vT) {
  __shared__ __attribute__((aligned(16))) bf16 a_tile[128 * 32];
  __shared__ __attribute__((aligned(16))) bf16 b_tile[128 * 32];
  const int tid = threadIdx.x;
  const int wid = tid >> 6;
  const int lane = tid & 63;
  const int lr = lane & 15;
  const int lg = lane >> 4;
  const int wr = wid >> 1;  // 0..1 row block of 64
  const int wc = wid & 1;   // 0..1 col block of 64

  // XCD mode-affinity remap (bijective over 384 = 8 XCD x 16 tiles x 3 modes)
  const int p = blockIdx.x + 128 * blockIdx.y;
  const int xcd = p & 7;
  const int s = p >> 3;            // 0..47 within XCD
  const int mode = s % 3;
  const int m0 = (xcd * 16 + s / 3) * 128;

  const bf16* wt = WT + (size_t)mode * 131072;

  int rowA[2], col8[2];
#pragma unroll
  for (int g = 0; g < 2; ++g) {
    const int idx8 = g * 256 + tid;
    rowA[g] = idx8 >> 2;
    col8[g] = (idx8 & 3) * 8;
  }

  f32x4 acc[4][4] = {};

  float4 fA[2][2];
  bf16x8 fB[2];
#pragma unroll
  for (int g = 0; g < 2; ++g) {  // prefetch kt = 0
    const float* src = x + (size_t)(m0 + rowA[g]) * CDIM + col8[g];
    fA[g][0] = *(const float4*)src;
    fA[g][1] = *(const float4*)(src + 4);
    fB[g] = *(const bf16x8*)(wt + (size_t)rowA[g] * CDIM + col8[g]);
  }

#pragma unroll 1
  for (int kt = 0; kt < 32; ++kt) {
    __syncthreads();  // prior iteration's fragment reads done
#pragma unroll
    for (int g = 0; g < 2; ++g) {
      bf16x8 av;
      av[0] = (bf16)fA[g][0].x; av[1] = (bf16)fA[g][0].y;
      av[2] = (bf16)fA[g][0].z; av[3] = (bf16)fA[g][0].w;
      av[4] = (bf16)fA[g][1].x; av[5] = (bf16)fA[g][1].y;
      av[6] = (bf16)fA[g][1].z; av[7] = (bf16)fA[g][1].w;
      *(bf16x8*)&a_tile[rowA[g] * 32 + col8[g]] = av;
      *(bf16x8*)&b_tile[rowA[g] * 32 + col8[g]] = fB[g];
    }
    __syncthreads();  // tiles staged
    if (kt + 1 < 32) {
#pragma unroll
      for (int g = 0; g < 2; ++g) {
        const float* src = x + (size_t)(m0 + rowA[g]) * CDIM + (kt + 1) * 32 + col8[g];
        fA[g][0] = *(const float4*)src;
        fA[g][1] = *(const float4*)(src + 4);
        fB[g] = *(const bf16x8*)(wt + (size_t)rowA[g] * CDIM + (kt + 1) * 32 + col8[g]);
      }
    }
    bf16x8 af[4], bfr[4];
#pragma unroll
    for (int r = 0; r < 4; ++r)
      af[r] = *(const bf16x8*)&a_tile[(wr * 64 + r * 16 + lr) * 32 + lg * 8];
#pragma unroll
    for (int c = 0; c < 4; ++c)
      bfr[c] = *(const bf16x8*)&b_tile[(wc * 64 + c * 16 + lr) * 32 + lg * 8];
#pragma unroll
    for (int r = 0; r < 4; ++r)
#pragma unroll
      for (int c = 0; c < 4; ++c)
        acc[r][c] = __builtin_amdgcn_mfma_f32_16x16x32_bf16(af[r], bfr[c], acc[r][c], 0, 0, 0);
  }

  if (mode < 2) {
    bf16* dst = (mode == 0) ? qb : kb;
    const float sc = (mode == 0) ? 0.03125f : 1.0f;  // fold C^-0.5 into q (exact)
#pragma unroll
    for (int r = 0; r < 4; ++r)
#pragma unroll
      for (int c = 0; c < 4; ++c)
#pragma unroll
        for (int j = 0; j < 4; ++j) {
          const int row = m0 + wr * 64 + r * 16 + lg * 4 + j;
          const int col = wc * 64 + c * 16 + lr;
          dst[(size_t)row * HDIM + col] = (bf16)(acc[r][c][j] * sc);
        }
  } else {
    // v pre-tiled: vTc[key>>6][d][key&63]; 16KB per 64-key block (contiguous)
#pragma unroll
    for (int r = 0; r < 4; ++r)
#pragma unroll
      for (int c = 0; c < 4; ++c) {
        const int row0 = m0 + wr * 64 + r * 16 + lg * 4;  // key index (4-aligned)
        const int col = wc * 64 + c * 16 + lr;            // d
        bf16x4 pv;
        pv[0] = (bf16)acc[r][c][0]; pv[1] = (bf16)acc[r][c][1];
        pv[2] = (bf16)acc[r][c][2]; pv[3] = (bf16)acc[r][c][3];
        *(bf16x4*)(vT + (size_t)(row0 >> 6) * 8192 + col * 64 + (row0 & 63)) = pv;
      }
  }
}

// ---------------------------------------------------------------------------
// Flash attention phase 1 (split-KV, block-cooperative, swapped QK^T) — R14
// verified. Block = 8 waves x 16 q-rows = 128 rows over one KV chunk. K tile
// (64x128) and V tile (128x64, pre-tiled vTc) staged in LDS, dbuf, via
// global_load_lds with pre-swizzled source (col ^= (row&7)<<4). S^T = mfma(K,Q):
// softmax in-lane; gated defer-max; lane-local l_. 80 KB LDS -> 2 blocks/CU.
// XCD chunk-affinity (maxc==8): XCD j runs chunks {(c=j,b=0,1),(c=7-j,b=2,3)}.
// ---------------------------------------------------------------------------
__global__ __launch_bounds__(512, 4) void attn_part(const bf16* __restrict__ qg,
                                                    const bf16* __restrict__ kb,
                                                    const bf16* __restrict__ vT,
                                                    bf16* __restrict__ po,
                                                    float* __restrict__ pm,
                                                    float* __restrict__ pl,
                                                    int cshift, int maxc) {
  // [2 buffers][K 16KB | V 16KB] + P 16KB = 80 KB
  __shared__ __attribute__((aligned(16))) char kv_lds[2][32768];
  __shared__ __attribute__((aligned(16))) bf16 p_lds[8][16][64];
  const int tid = threadIdx.x;
  const int wid = tid >> 6;       // 0..7
  const int lane = tid & 63;
  const int lr = lane & 15;
  const int lg = lane >> 4;

  // ---- XCD chunk-affinity remap (maxc==8 tier only) ----
  int bx = blockIdx.x, c = blockIdx.y, b = blockIdx.z;
  if (maxc == 8) {
    const int p = blockIdx.x + 32 * (blockIdx.y + 8 * blockIdx.z);
    const int xcd = p & 7;
    const int s = p >> 3;        // 0..127 within XCD
    const int combo = s >> 5;    // 0..3
    bx = s & 31;
    b = combo;
    c = (combo < 2) ? xcd : 7 - xcd;
  }

  const int qbase = bx * 128;
  const int kv0 = c << cshift;
  if (kv0 >= qbase + 128) return;  // block-uniform early exit
  const int kvend = min(kv0 + (1 << cshift), qbase + 128);  // 64-multiples
  const int nt = (kvend - kv0) >> 6;
  const int qr0 = qbase + wid * 16;
  const int grp = bx * 8 + wid;  // 0..255
  const size_t qrow = (size_t)b * TSEQ + qr0;

  // ---- staging source byte offsets (source pre-swizzled, dest linear) ----
  const int wbase = wid * 2048;  // each wave stages 2KB of K and 2KB of V
  int ksrc[2], vsrc[2];
#pragma unroll
  for (int i = 0; i < 2; ++i) {
    const int o = wbase + i * 1024 + lane * 16;  // linear dest byte in tile
    const int rk = o >> 8;                       // K row (256B rows)
    ksrc[i] = rk * 256 + ((o & 255) ^ ((rk & 7) << 4));
    const int rv = o >> 7;                       // V d-row (128B rows, contiguous tile)
    vsrc[i] = rv * 128 + ((o & 127) ^ ((rv & 7) << 4));
  }
  const char* kgb = (const char*)kb + (size_t)b * TSEQ * 256;  // + key*256B
  const char* vgb = (const char*)vT + (size_t)b * TSEQ * 256;  // + key*256B (tiled)

  // ---- fragment read bases (XOR split over disjoint bit fields) ----
  const int msk = (lr & 7) << 4;  // full mask bits 4-6
  const int m30 = (lr & 3) << 4;  // mask bits 4-5
  const int m6 = (lr & 4) << 4;   // mask bit 6
  const int lgx = (lg * 16) ^ m30;
  const int kreadA = lr * 256 + lgx + m6;         // d even (+128 for d=2)
  const int kreadB = lr * 256 + lgx + (64 ^ m6);  // d odd  (+128 for d=3)
  const int vreadA = 16384 + lr * 128 + lgx + m6;         // ks=0
  const int vreadB = 16384 + lr * 128 + lgx + (64 ^ m6);  // ks=1

  // Q fragments (hoisted): B-operand layout
  bf16x8 qf[4];
#pragma unroll
  for (int d = 0; d < 4; ++d)
    qf[d] = *(const bf16x8*)(qg + (qrow + lr) * HDIM + d * 32 + lg * 8);

  f32x4 o_[8] = {};              // O^T: o_[o][j] = O[q=lr][d = 16o + 4lg + j]
  float m_ = -1e30f, l_ = 0.0f;  // m_: row-uniform running max; l_: LANE-LOCAL

  // ---- prologue: stage tile 0 into buffer 0 ----
  {
    const char* ks = kgb + (size_t)kv0 * 256;
    const char* vs = vgb + (size_t)kv0 * 256;
#pragma unroll
    for (int i = 0; i < 2; ++i) {
      GLDS(ks + ksrc[i], &kv_lds[0][wbase + i * 1024]);
      GLDS(vs + vsrc[i], &kv_lds[0][16384 + wbase + i * 1024]);
    }
  }
  __syncthreads();  // drains vmcnt: tile 0 resident

  int cur = 0;
  for (int t = 0; t < nt; ++t) {
    const int kvt = kv0 + (t << 6);
    // ---- issue next tile's staging (flies under compute) ----
    if (t + 1 < nt) {
      const char* ks = kgb + (size_t)(kvt + 64) * 256;
      const char* vs = vgb + (size_t)(kvt + 64) * 256;
#pragma unroll
      for (int i = 0; i < 2; ++i) {
        GLDS(ks + ksrc[i], &kv_lds[cur ^ 1][wbase + i * 1024]);
        GLDS(vs + vsrc[i], &kv_lds[cur ^ 1][16384 + wbase + i * 1024]);
      }
    }
    // ---- compute (waves whose rows end before this tile just barrier) ----
    if (kvt < qr0 + 16) {
      const char* kbuf = kv_lds[cur];
      // S^T = mfma(A=K, B=Q): s[nf][j] = S[q=lr][key = kvt + nf*16 + lg*4 + j]
      f32x4 s[4] = {};
      __builtin_amdgcn_s_setprio(1);
#pragma unroll
      for (int nf = 0; nf < 4; ++nf) {
        const char* kb0 = kbuf + nf * 4096;
        bf16x8 kf;
        kf = *(const bf16x8*)(kb0 + kreadA);
        s[nf] = __builtin_amdgcn_mfma_f32_16x16x32_bf16(kf, qf[0], s[nf], 0, 0, 0);
        kf = *(const bf16x8*)(kb0 + kreadB);
        s[nf] = __builtin_amdgcn_mfma_f32_16x16x32_bf16(kf, qf[1], s[nf], 0, 0, 0);
        kf = *(const bf16x8*)(kb0 + kreadA + 128);
        s[nf] = __builtin_amdgcn_mfma_f32_16x16x32_bf16(kf, qf[2], s[nf], 0, 0, 0);
        kf = *(const bf16x8*)(kb0 + kreadB + 128);
        s[nf] = __builtin_amdgcn_mfma_f32_16x16x32_bf16(kf, qf[3], s[nf], 0, 0, 0);
      }
      __builtin_amdgcn_s_setprio(0);
      // causal mask (only tiles crossing the diagonal)
      if (kvt + 63 >= qr0) {
        const int q = qr0 + lr;
#pragma unroll
        for (int nf = 0; nf < 4; ++nf)
#pragma unroll
          for (int j = 0; j < 4; ++j)
            if (kvt + nf * 16 + lg * 4 + j > q) s[nf][j] = -1e30f;
      }
      // lane-local row max over this lane's 16 scores
      float rloc = fmaxf(fmaxf(s[0][0], s[0][1]), fmaxf(s[0][2], s[0][3]));
#pragma unroll
      for (int nf = 1; nf < 4; ++nf)
        rloc = fmaxf(rloc, fmaxf(fmaxf(s[nf][0], s[nf][1]), fmaxf(s[nf][2], s[nf][3])));
      // gated defer-max: cross-lane reduce + rescale only when needed
      if (!__all(rloc <= m_ + 8.0f)) {
        float rmax = fmaxf(rloc, __shfl_xor(rloc, 16));
        rmax = fmaxf(rmax, __shfl_xor(rmax, 32));
        const float mn = fmaxf(m_, rmax);
        const float al = exp2f((m_ - mn) * L2E);
        m_ = mn;
        l_ *= al;
#pragma unroll
        for (int o = 0; o < 8; ++o)
#pragma unroll
          for (int j = 0; j < 4; ++j) o_[o][j] *= al;
      }
      float rsum = 0.0f;
#pragma unroll
      for (int nf = 0; nf < 4; ++nf)
#pragma unroll
        for (int j = 0; j < 4; ++j) {
          s[nf][j] = exp2f((s[nf][j] - m_) * L2E);
          rsum += s[nf][j];
        }
      l_ += rsum;  // lane-local; cross-lane reduced once at the end
      // P^T -> swizzled p_lds [q-row][key], one b64 write per nf
      {
        char* pw = (char*)p_lds + wid * 2048 + lr * 128;
#pragma unroll
        for (int nf = 0; nf < 4; ++nf) {
          uint2 w2;
          w2.x = pkbf(s[nf][0], s[nf][1]); w2.y = pkbf(s[nf][2], s[nf][3]);
          *(uint2*)(pw + (((nf * 32) + lg * 8) ^ msk)) = w2;
        }
      }
      asm volatile("s_waitcnt lgkmcnt(0)" ::: "memory");
      __builtin_amdgcn_sched_barrier(0);  // keep dependent MFMAs below the wait
      // O^T += V^T P^T  (A = V^T frag; B = P^T frag, swizzled read)
      const char* pr = (const char*)p_lds + wid * 2048 + lr * 128;
      bf16x8 pf0 = *(const bf16x8*)(pr + lgx + m6);
      bf16x8 pf1 = *(const bf16x8*)(pr + lgx + (64 ^ m6));
      __builtin_amdgcn_s_setprio(1);
#pragma unroll
      for (int o = 0; o < 8; ++o) {
        bf16x8 vf;
        vf = *(const bf16x8*)(kbuf + vreadA + o * 2048);
        o_[o] = __builtin_amdgcn_mfma_f32_16x16x32_bf16(vf, pf0, o_[o], 0, 0, 0);
        vf = *(const bf16x8*)(kbuf + vreadB + o * 2048);
        o_[o] = __builtin_amdgcn_mfma_f32_16x16x32_bf16(vf, pf1, o_[o], 0, 0, 0);
      }
      __builtin_amdgcn_s_setprio(0);
    }
    __syncthreads();  // staging (vmcnt) drained; everyone done with buf[cur]
    cur ^= 1;
  }

  // ---- finalize lane-local l_ (one cross-lane reduce per kernel) ----
  l_ += __shfl_xor(l_, 16);
  l_ += __shfl_xor(l_, 32);

  // ---- write unnormalized partials: lane owns q-row lr ----
  const size_t slot = (size_t)(b * 256 + grp) * maxc + c;
  bf16* pob = po + slot * (16 * HDIM);
#pragma unroll
  for (int o = 0; o < 8; ++o) {
    bf16x4 pv;
    pv[0] = (bf16)o_[o][0]; pv[1] = (bf16)o_[o][1];
    pv[2] = (bf16)o_[o][2]; pv[3] = (bf16)o_[o][3];
    *(bf16x4*)(pob + lr * HDIM + o * 16 + lg * 4) = pv;
  }
  if (lg == 0) {
    pm[slot * 16 + lr] = m_;
    pl[slot * 16 + lr] = l_;
  }
}

// ---------------------------------------------------------------------------
// Flash attention phase 2: merge <=maxc partials per (batch, group).
// ---------------------------------------------------------------------------
__global__ __launch_bounds__(256) void attn_merge(const bf16* __restrict__ po,
                                                  const float* __restrict__ pm,
                                                  const float* __restrict__ pl,
                                                  float* __restrict__ out,
                                                  int cshift, int maxc) {
  const int bg = blockIdx.x;          // b*256 + g
  const int g = bg & 255;
  const int nch = ((g << 4) >> cshift) + 1;
  const int row = threadIdx.x >> 4;
  const int d8 = (threadIdx.x & 15) * 8;
  const size_t slot0 = (size_t)bg * maxc;

  float M = -1e30f;
  for (int c = 0; c < nch; ++c) M = fmaxf(M, pm[(slot0 + c) * 16 + row]);
  float L = 0.0f;
  float acc[8] = {};
  for (int c = 0; c < nch; ++c) {
    const float w = exp2f((pm[(slot0 + c) * 16 + row] - M) * L2E);
    L += w * pl[(slot0 + c) * 16 + row];
    const bf16x8 v = *(const bf16x8*)(po + (slot0 + c) * (16 * HDIM) + row * HDIM + d8);
#pragma unroll
    for (int i = 0; i < 8; ++i) acc[i] += w * (float)v[i];
  }
  const float inv = 1.0f / L;
  f32x4 r0, r1;
#pragma unroll
  for (int i = 0; i < 4; ++i) { r0[i] = acc[i] * inv; r1[i] = acc[i + 4] * inv; }
  float* dst = out + (size_t)bg * (16 * HDIM) + row * HDIM + d8;
  *(f32x4*)dst = r0;
  *(f32x4*)(dst + 4) = r1;
}

// ---------------------------------------------------------------------------
extern "C" void kernel_launch(void* const* d_in, const int* in_sizes, int n_in,
                              void* d_out, int out_size, void* d_ws, size_t ws_size,
                              hipStream_t stream) {
  const float* x  = (const float*)d_in[0];
  const float* Wk = (const float*)d_in[1];
  const float* Wq = (const float*)d_in[2];
  const float* Wv = (const float*)d_in[3];
  float* out = (float*)d_out;

  char* ws = (char*)d_ws;
  bf16* qb = (bf16*)(ws);                   // [16384][128] bf16, 4 MB
  bf16* kb = (bf16*)(ws + 4194304);         // [16384][128] bf16, 4 MB
  bf16* vT = (bf16*)(ws + 8388608);         // vTc[256][128][64] bf16, 4 MB
  bf16* WT = (bf16*)(ws + 12582912);        // [3][128][1024] bf16, 768 KB
  const size_t pbase = 13369344;

  // choose KV-chunking tier by available workspace:
  //   per-slot bytes: 16*128*2 (po) + 2*16*4 (pm,pl) = 4224; slots = 1024*maxc
  int cshift, maxc;
  if (ws_size >= pbase + 8ull * 1024 * 4224) { cshift = 9;  maxc = 8; }       // 512-key chunks
  else if (ws_size >= pbase + 4ull * 1024 * 4224) { cshift = 10; maxc = 4; }  // 1024-key
  else { cshift = 12; maxc = 1; }                                             // no split
  bf16* po = (bf16*)(ws + pbase);
  float* pm = (float*)(ws + pbase + (size_t)maxc * 1024 * 16 * 128 * 2);
  float* pl = pm + (size_t)maxc * 1024 * 16;

  wt_prep<<<dim3(512, 3), 256, 0, stream>>>(Wq, Wk, Wv, WT);
  qkv_gemm<<<dim3(128, 3), 256, 0, stream>>>(x, WT, qb, kb, vT);
  attn_part<<<dim3(32, maxc, 4), 512, 0, stream>>>(qb, kb, vT, po, pm, pl, cshift, maxc);
  attn_merge<<<1024, 256, 0, stream>>>(po, pm, pl, out, cshift, maxc);
}

// Round 18
// 90.878 us; speedup vs baseline: 1.0631x; 1.0000x over previous
//
#include <hip/hip_runtime.h>

// Head attention forward: x[4,4096,1024] f32, Wk/Wq/Wv [1024,128] f32 -> out[4,4096,128] f32
// Pipeline: (1) W transpose->bf16, (2) QKV projection via bf16 MFMA GEMM (3 modes,
// XCD mode-affinity; A/B reg-prefetched; q pre-scaled, v PRE-TILED vTc), (3)
// split-KV flash attention: 8 waves x 16 q-rows, K+V LDS-staged (2-buffer,
// COUNTED-vmcnt pipeline: s_waitcnt vmcnt(4) + raw s_barrier, compute, raw
// s_barrier, stage t+2 — staging loads stay in flight across barriers, never
// drained mid-loop), swapped QK^T, in-lane softmax, gated defer-max, lane-local
// l_, XCD chunk-affinity remap; phase 2 = merge.

typedef __bf16 bf16;
typedef bf16 bf16x8 __attribute__((ext_vector_type(8)));
typedef bf16 bf16x4 __attribute__((ext_vector_type(4)));
typedef float f32x4 __attribute__((ext_vector_type(4)));

#define L2E 1.4426950408889634f
#define TSEQ 4096
#define CDIM 1024
#define HDIM 128
#define MROWS 16384  // B*T

// async global->LDS, 16B per lane; LDS dest = wave-uniform base + lane*16
#define GLDS(g, l)                                              \
  __builtin_amdgcn_global_load_lds(                             \
      (__attribute__((address_space(1))) void*)(g),             \
      (__attribute__((address_space(3))) void*)(l), 16, 0, 0)

// pack two floats into one dword of bf16 (lo = a, hi = b)
static __device__ inline unsigned pkbf(float a, float b) {
  union { bf16 h; unsigned short u; } ua, ub;
  ua.h = (bf16)a; ub.h = (bf16)b;
  return ((unsigned)ub.u << 16) | (unsigned)ua.u;
}

// ---------------------------------------------------------------------------
// prep: W [1024][128] f32 (in,out)  ->  WT [128][1024] bf16  (out-major)
// ---------------------------------------------------------------------------
__global__ __launch_bounds__(256) void wt_prep(const float* __restrict__ Wq,
                                               const float* __restrict__ Wk,
                                               const float* __restrict__ Wv,
                                               bf16* __restrict__ WT) {
  const int mode = blockIdx.y;
  const float* W = (mode == 0) ? Wq : (mode == 1) ? Wk : Wv;
  const int idx = blockIdx.x * 256 + threadIdx.x;  // 0..131071 over [128][1024]
  const int n = idx >> 10;                         // head dim 0..127
  const int k = idx & 1023;                        // in dim  0..1023
  WT[(size_t)mode * 131072 + idx] = (bf16)W[(size_t)k * HDIM + n];
}

// ---------------------------------------------------------------------------
// QKV GEMM (R10-verified schedule + XCD mode-affinity): C = x @ W per mode.
// 128x128 tile, BK=32, 4 waves (2x2 of 64x64), mfma_f32_16x16x32_bf16.
// mode 0: qb scaled 1/32; mode 1: kb; mode 2: vTc[key>>6][d][key&63] pre-tiled.
// ---------------------------------------------------------------------------
__global__ __launch_bounds__(256) void qkv_gemm(const float* __restrict__ x,
                                                const bf16* __restrict__ WT,
                                                bf16* __restrict__ qb,
                                                bf16* __restrict__ kb,
                                                bf16* __restrict__ vT) {
  __shared__ __attribute__((aligned(16))) bf16 a_tile[128 * 32];
  __shared__ __attribute__((aligned(16))) bf16 b_tile[128 * 32];
  const int tid = threadIdx.x;
  const int wid = tid >> 6;
  const int lane = tid & 63;
  const int lr = lane & 15;
  const int lg = lane >> 4;
  const int wr = wid >> 1;  // 0..1 row block of 64
  const int wc = wid & 1;   // 0..1 col block of 64

  // XCD mode-affinity remap (bijective over 384 = 8 XCD x 16 tiles x 3 modes)
  const int p = blockIdx.x + 128 * blockIdx.y;
  const int xcd = p & 7;
  const int s = p >> 3;            // 0..47 within XCD
  const int mode = s % 3;
  const int m0 = (xcd * 16 + s / 3) * 128;

  const bf16* wt = WT + (size_t)mode * 131072;

  int rowA[2], col8[2];
#pragma unroll
  for (int g = 0; g < 2; ++g) {
    const int idx8 = g * 256 + tid;
    rowA[g] = idx8 >> 2;
    col8[g] = (idx8 & 3) * 8;
  }

  f32x4 acc[4][4] = {};

  float4 fA[2][2];
  bf16x8 fB[2];
#pragma unroll
  for (int g = 0; g < 2; ++g) {  // prefetch kt = 0
    const float* src = x + (size_t)(m0 + rowA[g]) * CDIM + col8[g];
    fA[g][0] = *(const float4*)src;
    fA[g][1] = *(const float4*)(src + 4);
    fB[g] = *(const bf16x8*)(wt + (size_t)rowA[g] * CDIM + col8[g]);
  }

#pragma unroll 1
  for (int kt = 0; kt < 32; ++kt) {
    __syncthreads();  // prior iteration's fragment reads done
#pragma unroll
    for (int g = 0; g < 2; ++g) {
      bf16x8 av;
      av[0] = (bf16)fA[g][0].x; av[1] = (bf16)fA[g][0].y;
      av[2] = (bf16)fA[g][0].z; av[3] = (bf16)fA[g][0].w;
      av[4] = (bf16)fA[g][1].x; av[5] = (bf16)fA[g][1].y;
      av[6] = (bf16)fA[g][1].z; av[7] = (bf16)fA[g][1].w;
      *(bf16x8*)&a_tile[rowA[g] * 32 + col8[g]] = av;
      *(bf16x8*)&b_tile[rowA[g] * 32 + col8[g]] = fB[g];
    }
    __syncthreads();  // tiles staged
    if (kt + 1 < 32) {
#pragma unroll
      for (int g = 0; g < 2; ++g) {
        const float* src = x + (size_t)(m0 + rowA[g]) * CDIM + (kt + 1) * 32 + col8[g];
        fA[g][0] = *(const float4*)src;
        fA[g][1] = *(const float4*)(src + 4);
        fB[g] = *(const bf16x8*)(wt + (size_t)rowA[g] * CDIM + (kt + 1) * 32 + col8[g]);
      }
    }
    bf16x8 af[4], bfr[4];
#pragma unroll
    for (int r = 0; r < 4; ++r)
      af[r] = *(const bf16x8*)&a_tile[(wr * 64 + r * 16 + lr) * 32 + lg * 8];
#pragma unroll
    for (int c = 0; c < 4; ++c)
      bfr[c] = *(const bf16x8*)&b_tile[(wc * 64 + c * 16 + lr) * 32 + lg * 8];
#pragma unroll
    for (int r = 0; r < 4; ++r)
#pragma unroll
      for (int c = 0; c < 4; ++c)
        acc[r][c] = __builtin_amdgcn_mfma_f32_16x16x32_bf16(af[r], bfr[c], acc[r][c], 0, 0, 0);
  }

  if (mode < 2) {
    bf16* dst = (mode == 0) ? qb : kb;
    const float sc = (mode == 0) ? 0.03125f : 1.0f;  // fold C^-0.5 into q (exact)
#pragma unroll
    for (int r = 0; r < 4; ++r)
#pragma unroll
      for (int c = 0; c < 4; ++c)
#pragma unroll
        for (int j = 0; j < 4; ++j) {
          const int row = m0 + wr * 64 + r * 16 + lg * 4 + j;
          const int col = wc * 64 + c * 16 + lr;
          dst[(size_t)row * HDIM + col] = (bf16)(acc[r][c][j] * sc);
        }
  } else {
    // v pre-tiled: vTc[key>>6][d][key&63]; 16KB per 64-key block (contiguous)
#pragma unroll
    for (int r = 0; r < 4; ++r)
#pragma unroll
      for (int c = 0; c < 4; ++c) {
        const int row0 = m0 + wr * 64 + r * 16 + lg * 4;  // key index (4-aligned)
        const int col = wc * 64 + c * 16 + lr;            // d
        bf16x4 pv;
        pv[0] = (bf16)acc[r][c][0]; pv[1] = (bf16)acc[r][c][1];
        pv[2] = (bf16)acc[r][c][2]; pv[3] = (bf16)acc[r][c][3];
        *(bf16x4*)(vT + (size_t)(row0 >> 6) * 8192 + col * 64 + (row0 & 63)) = pv;
      }
  }
}

// ---------------------------------------------------------------------------
// Flash attention phase 1 (split-KV, block-cooperative, swapped QK^T).
// Block = 8 waves x 16 q-rows = 128 rows over one KV chunk. K tile (64x128) and
// V tile (128x64, pre-tiled vTc) staged via global_load_lds (pre-swizzled
// source) into a 2-BUFFER COUNTED-vmcnt pipeline: per tile
//   {s_waitcnt vmcnt(4) [0 on last]; s_barrier; compute buf[t&1]; s_barrier;
//    stage t+2 -> buf[t&1]}
// — the next tile's 4 staging loads stay in flight across both barriers
// (never drained mid-loop). Same 80 KB LDS -> 2 blocks/CU as R14 (isolates the
// drain effect from occupancy, unlike the R7/R8 3-buffer test). S^T = mfma(K,Q);
// softmax in-lane; gated defer-max; lane-local l_. XCD chunk-affinity remap.
// ---------------------------------------------------------------------------
__global__ __launch_bounds__(512, 4) void attn_part(const bf16* __restrict__ qg,
                                                    const bf16* __restrict__ kb,
                                                    const bf16* __restrict__ vT,
                                                    bf16* __restrict__ po,
                                                    float* __restrict__ pm,
                                                    float* __restrict__ pl,
                                                    int cshift, int maxc) {
  // [2 buffers][K 16KB | V 16KB] + P 16KB = 80 KB
  __shared__ __attribute__((aligned(16))) char kv_lds[2][32768];
  __shared__ __attribute__((aligned(16))) bf16 p_lds[8][16][64];
  const int tid = threadIdx.x;
  const int wid = tid >> 6;       // 0..7
  const int lane = tid & 63;
  const int lr = lane & 15;
  const int lg = lane >> 4;

  // ---- XCD chunk-affinity remap (maxc==8 tier only) ----
  int bx = blockIdx.x, c = blockIdx.y, b = blockIdx.z;
  if (maxc == 8) {
    const int p = blockIdx.x + 32 * (blockIdx.y + 8 * blockIdx.z);
    const int xcd = p & 7;
    const int s = p >> 3;        // 0..127 within XCD
    const int combo = s >> 5;    // 0..3
    bx = s & 31;
    b = combo;
    c = (combo < 2) ? xcd : 7 - xcd;
  }

  const int qbase = bx * 128;
  const int kv0 = c << cshift;
  if (kv0 >= qbase + 128) return;  // block-uniform early exit
  const int kvend = min(kv0 + (1 << cshift), qbase + 128);  // 64-multiples
  const int nt = (kvend - kv0) >> 6;
  const int qr0 = qbase + wid * 16;
  const int grp = bx * 8 + wid;  // 0..255
  const size_t qrow = (size_t)b * TSEQ + qr0;

  // ---- staging source byte offsets (source pre-swizzled, dest linear) ----
  const int wbase = wid * 2048;  // each wave stages 2KB of K and 2KB of V
  int ksrc[2], vsrc[2];
#pragma unroll
  for (int i = 0; i < 2; ++i) {
    const int o = wbase + i * 1024 + lane * 16;  // linear dest byte in tile
    const int rk = o >> 8;                       // K row (256B rows)
    ksrc[i] = rk * 256 + ((o & 255) ^ ((rk & 7) << 4));
    const int rv = o >> 7;                       // V d-row (128B rows, contiguous tile)
    vsrc[i] = rv * 128 + ((o & 127) ^ ((rv & 7) << 4));
  }
  const char* kgb = (const char*)kb + (size_t)b * TSEQ * 256;  // + key*256B
  const char* vgb = (const char*)vT + (size_t)b * TSEQ * 256;  // + key*256B (tiled)

  // ---- fragment read bases (XOR split over disjoint bit fields) ----
  const int msk = (lr & 7) << 4;  // full mask bits 4-6
  const int m30 = (lr & 3) << 4;  // mask bits 4-5
  const int m6 = (lr & 4) << 4;   // mask bit 6
  const int lgx = (lg * 16) ^ m30;
  const int kreadA = lr * 256 + lgx + m6;         // d even (+128 for d=2)
  const int kreadB = lr * 256 + lgx + (64 ^ m6);  // d odd  (+128 for d=3)
  const int vreadA = 16384 + lr * 128 + lgx + m6;         // ks=0
  const int vreadB = 16384 + lr * 128 + lgx + (64 ^ m6);  // ks=1

  // Q fragments (hoisted): B-operand layout
  bf16x8 qf[4];
#pragma unroll
  for (int d = 0; d < 4; ++d)
    qf[d] = *(const bf16x8*)(qg + (qrow + lr) * HDIM + d * 32 + lg * 8);
  // drain Q loads so the manual vmcnt counts only staging ops
  asm volatile("s_waitcnt vmcnt(0)" ::: "memory");

  f32x4 o_[8] = {};              // O^T: o_[o][j] = O[q=lr][d = 16o + 4lg + j]
  float m_ = -1e30f, l_ = 0.0f;  // m_: row-uniform running max; l_: LANE-LOCAL

  // ---- prologue: stage tile 0 -> buf0, tile 1 -> buf1 ----
  {
    const char* ks = kgb + (size_t)kv0 * 256;
    const char* vs = vgb + (size_t)kv0 * 256;
#pragma unroll
    for (int i = 0; i < 2; ++i) {
      GLDS(ks + ksrc[i], &kv_lds[0][wbase + i * 1024]);
      GLDS(vs + vsrc[i], &kv_lds[0][16384 + wbase + i * 1024]);
    }
  }
  if (nt > 1) {
    const char* ks = kgb + (size_t)(kv0 + 64) * 256;
    const char* vs = vgb + (size_t)(kv0 + 64) * 256;
#pragma unroll
    for (int i = 0; i < 2; ++i) {
      GLDS(ks + ksrc[i], &kv_lds[1][wbase + i * 1024]);
      GLDS(vs + vsrc[i], &kv_lds[1][16384 + wbase + i * 1024]);
    }
  }

#pragma unroll 1
  for (int t = 0; t < nt; ++t) {
    const int kvt = kv0 + (t << 6);
    // counted wait: tile t's 4 loads are oldest; tile t+1's 4 stay in flight
    if (t + 1 < nt) asm volatile("s_waitcnt vmcnt(4)" ::: "memory");
    else            asm volatile("s_waitcnt vmcnt(0)" ::: "memory");
    __builtin_amdgcn_s_barrier();        // all waves' tile-t portions resident
    __builtin_amdgcn_sched_barrier(0);   // nothing hoists above the wait
    if (kvt < qr0 + 16) {
      const char* kbuf = kv_lds[t & 1];
      // S^T = mfma(A=K, B=Q): s[nf][j] = S[q=lr][key = kvt + nf*16 + lg*4 + j]
      f32x4 s[4] = {};
      __builtin_amdgcn_s_setprio(1);
#pragma unroll
      for (int nf = 0; nf < 4; ++nf) {
        const char* kb0 = kbuf + nf * 4096;
        bf16x8 kf;
        kf = *(const bf16x8*)(kb0 + kreadA);
        s[nf] = __builtin_amdgcn_mfma_f32_16x16x32_bf16(kf, qf[0], s[nf], 0, 0, 0);
        kf = *(const bf16x8*)(kb0 + kreadB);
        s[nf] = __builtin_amdgcn_mfma_f32_16x16x32_bf16(kf, qf[1], s[nf], 0, 0, 0);
        kf = *(const bf16x8*)(kb0 + kreadA + 128);
        s[nf] = __builtin_amdgcn_mfma_f32_16x16x32_bf16(kf, qf[2], s[nf], 0, 0, 0);
        kf = *(const bf16x8*)(kb0 + kreadB + 128);
        s[nf] = __builtin_amdgcn_mfma_f32_16x16x32_bf16(kf, qf[3], s[nf], 0, 0, 0);
      }
      __builtin_amdgcn_s_setprio(0);
      // causal mask (only tiles crossing the diagonal)
      if (kvt + 63 >= qr0) {
        const int q = qr0 + lr;
#pragma unroll
        for (int nf = 0; nf < 4; ++nf)
#pragma unroll
          for (int j = 0; j < 4; ++j)
            if (kvt + nf * 16 + lg * 4 + j > q) s[nf][j] = -1e30f;
      }
      // lane-local row max over this lane's 16 scores
      float rloc = fmaxf(fmaxf(s[0][0], s[0][1]), fmaxf(s[0][2], s[0][3]));
#pragma unroll
      for (int nf = 1; nf < 4; ++nf)
        rloc = fmaxf(rloc, fmaxf(fmaxf(s[nf][0], s[nf][1]), fmaxf(s[nf][2], s[nf][3])));
      // gated defer-max: cross-lane reduce + rescale only when needed
      if (!__all(rloc <= m_ + 8.0f)) {
        float rmax = fmaxf(rloc, __shfl_xor(rloc, 16));
        rmax = fmaxf(rmax, __shfl_xor(rmax, 32));
        const float mn = fmaxf(m_, rmax);
        const float al = exp2f((m_ - mn) * L2E);
        m_ = mn;
        l_ *= al;
#pragma unroll
        for (int o = 0; o < 8; ++o)
#pragma unroll
          for (int j = 0; j < 4; ++j) o_[o][j] *= al;
      }
      float rsum = 0.0f;
#pragma unroll
      for (int nf = 0; nf < 4; ++nf)
#pragma unroll
        for (int j = 0; j < 4; ++j) {
          s[nf][j] = exp2f((s[nf][j] - m_) * L2E);
          rsum += s[nf][j];
        }
      l_ += rsum;  // lane-local; cross-lane reduced once at the end
      // P^T -> swizzled p_lds [q-row][key], one b64 write per nf
      {
        char* pw = (char*)p_lds + wid * 2048 + lr * 128;
#pragma unroll
        for (int nf = 0; nf < 4; ++nf) {
          uint2 w2;
          w2.x = pkbf(s[nf][0], s[nf][1]); w2.y = pkbf(s[nf][2], s[nf][3]);
          *(uint2*)(pw + (((nf * 32) + lg * 8) ^ msk)) = w2;
        }
      }
      asm volatile("s_waitcnt lgkmcnt(0)" ::: "memory");
      __builtin_amdgcn_sched_barrier(0);  // keep dependent MFMAs below the wait
      // O^T += V^T P^T  (A = V^T frag; B = P^T frag, swizzled read)
      const char* pr = (const char*)p_lds + wid * 2048 + lr * 128;
      bf16x8 pf0 = *(const bf16x8*)(pr + lgx + m6);
      bf16x8 pf1 = *(const bf16x8*)(pr + lgx + (64 ^ m6));
      __builtin_amdgcn_s_setprio(1);
#pragma unroll
      for (int o = 0; o < 8; ++o) {
        bf16x8 vf;
        vf = *(const bf16x8*)(kbuf + vreadA + o * 2048);
        o_[o] = __builtin_amdgcn_mfma_f32_16x16x32_bf16(vf, pf0, o_[o], 0, 0, 0);
        vf = *(const bf16x8*)(kbuf + vreadB + o * 2048);
        o_[o] = __builtin_amdgcn_mfma_f32_16x16x32_bf16(vf, pf1, o_[o], 0, 0, 0);
      }
      __builtin_amdgcn_s_setprio(0);
    }
    __builtin_amdgcn_s_barrier();  // all waves done reading buf[t&1]
    // ---- issue staging for tile t+2 into the just-freed buffer ----
    if (t + 2 < nt) {
      const char* ks = kgb + (size_t)(kvt + 128) * 256;
      const char* vs = vgb + (size_t)(kvt + 128) * 256;
      char* db = kv_lds[t & 1];
#pragma unroll
      for (int i = 0; i < 2; ++i) {
        GLDS(ks + ksrc[i], db + wbase + i * 1024);
        GLDS(vs + vsrc[i], db + 16384 + wbase + i * 1024);
      }
    }
  }

  // ---- finalize lane-local l_ (one cross-lane reduce per kernel) ----
  l_ += __shfl_xor(l_, 16);
  l_ += __shfl_xor(l_, 32);

  // ---- write unnormalized partials: lane owns q-row lr ----
  const size_t slot = (size_t)(b * 256 + grp) * maxc + c;
  bf16* pob = po + slot * (16 * HDIM);
#pragma unroll
  for (int o = 0; o < 8; ++o) {
    bf16x4 pv;
    pv[0] = (bf16)o_[o][0]; pv[1] = (bf16)o_[o][1];
    pv[2] = (bf16)o_[o][2]; pv[3] = (bf16)o_[o][3];
    *(bf16x4*)(pob + lr * HDIM + o * 16 + lg * 4) = pv;
  }
  if (lg == 0) {
    pm[slot * 16 + lr] = m_;
    pl[slot * 16 + lr] = l_;
  }
}

// ---------------------------------------------------------------------------
// Flash attention phase 2: merge <=maxc partials per (batch, group).
// ---------------------------------------------------------------------------
__global__ __launch_bounds__(256) void attn_merge(const bf16* __restrict__ po,
                                                  const float* __restrict__ pm,
                                                  const float* __restrict__ pl,
                                                  float* __restrict__ out,
                                                  int cshift, int maxc) {
  const int bg = blockIdx.x;          // b*256 + g
  const int g = bg & 255;
  const int nch = ((g << 4) >> cshift) + 1;
  const int row = threadIdx.x >> 4;
  const int d8 = (threadIdx.x & 15) * 8;
  const size_t slot0 = (size_t)bg * maxc;

  float M = -1e30f;
  for (int c = 0; c < nch; ++c) M = fmaxf(M, pm[(slot0 + c) * 16 + row]);
  float L = 0.0f;
  float acc[8] = {};
  for (int c = 0; c < nch; ++c) {
    const float w = exp2f((pm[(slot0 + c) * 16 + row] - M) * L2E);
    L += w * pl[(slot0 + c) * 16 + row];
    const bf16x8 v = *(const bf16x8*)(po + (slot0 + c) * (16 * HDIM) + row * HDIM + d8);
#pragma unroll
    for (int i = 0; i < 8; ++i) acc[i] += w * (float)v[i];
  }
  const float inv = 1.0f / L;
  f32x4 r0, r1;
#pragma unroll
  for (int i = 0; i < 4; ++i) { r0[i] = acc[i] * inv; r1[i] = acc[i + 4] * inv; }
  float* dst = out + (size_t)bg * (16 * HDIM) + row * HDIM + d8;
  *(f32x4*)dst = r0;
  *(f32x4*)(dst + 4) = r1;
}

// ---------------------------------------------------------------------------
extern "C" void kernel_launch(void* const* d_in, const int* in_sizes, int n_in,
                              void* d_out, int out_size, void* d_ws, size_t ws_size,
                              hipStream_t stream) {
  const float* x  = (const float*)d_in[0];
  const float* Wk = (const float*)d_in[1];
  const float* Wq = (const float*)d_in[2];
  const float* Wv = (const float*)d_in[3];
  float* out = (float*)d_out;

  char* ws = (char*)d_ws;
  bf16* qb = (bf16*)(ws);                   // [16384][128] bf16, 4 MB
  bf16* kb = (bf16*)(ws + 4194304);         // [16384][128] bf16, 4 MB
  bf16* vT = (bf16*)(ws + 8388608);         // vTc[256][128][64] bf16, 4 MB
  bf16* WT = (bf16*)(ws + 12582912);        // [3][128][1024] bf16, 768 KB
  const size_t pbase = 13369344;

  // choose KV-chunking tier by available workspace:
  //   per-slot bytes: 16*128*2 (po) + 2*16*4 (pm,pl) = 4224; slots = 1024*maxc
  int cshift, maxc;
  if (ws_size >= pbase + 8ull * 1024 * 4224) { cshift = 9;  maxc = 8; }       // 512-key chunks
  else if (ws_size >= pbase + 4ull * 1024 * 4224) { cshift = 10; maxc = 4; }  // 1024-key
  else { cshift = 12; maxc = 1; }                                             // no split
  bf16* po = (bf16*)(ws + pbase);
  float* pm = (float*)(ws + pbase + (size_t)maxc * 1024 * 16 * 128 * 2);
  float* pl = pm + (size_t)maxc * 1024 * 16;

  wt_prep<<<dim3(512, 3), 256, 0, stream>>>(Wq, Wk, Wv, WT);
  qkv_gemm<<<dim3(128, 3), 256, 0, stream>>>(x, WT, qb, kb, vT);
  attn_part<<<dim3(32, maxc, 4), 512, 0, stream>>>(qb, kb, vT, po, pm, pl, cshift, maxc);
  attn_merge<<<1024, 256, 0, stream>>>(po, pm, pl, out, cshift, maxc);
}

// Round 19
// 90.067 us; speedup vs baseline: 1.0727x; 1.0090x over previous
//
#include <hip/hip_runtime.h>

// Head attention forward: x[4,4096,1024] f32, Wk/Wq/Wv [1024,128] f32 -> out[4,4096,128] f32
// Best-measured configuration (R14, 90.2us) + max3-chained row reductions.
// Pipeline: (1) W transpose->bf16, (2) QKV projection via bf16 MFMA GEMM (3 modes;
// q pre-scaled by C^-0.5, v stored PRE-TILED vTc[keyblk][128 d][64 key]; A/B
// reg-prefetched one K-step ahead), (3) split-KV flash attention: 8 waves x 16
// q-rows share LDS-staged K+V (dbuf global_load_lds, pre-swizzled source),
// swapped QK^T, in-lane softmax with gated defer-max, lane-local l_, XCD
// chunk-affinity remap (verified: FETCH 32->13MB, attn 62->53us); (4) merge.

typedef __bf16 bf16;
typedef bf16 bf16x8 __attribute__((ext_vector_type(8)));
typedef bf16 bf16x4 __attribute__((ext_vector_type(4)));
typedef float f32x4 __attribute__((ext_vector_type(4)));

#define L2E 1.4426950408889634f
#define TSEQ 4096
#define CDIM 1024
#define HDIM 128
#define MROWS 16384  // B*T

// async global->LDS, 16B per lane; LDS dest = wave-uniform base + lane*16
#define GLDS(g, l)                                              \
  __builtin_amdgcn_global_load_lds(                             \
      (__attribute__((address_space(1))) void*)(g),             \
      (__attribute__((address_space(3))) void*)(l), 16, 0, 0)

// pack two floats into one dword of bf16 (lo = a, hi = b)
static __device__ inline unsigned pkbf(float a, float b) {
  union { bf16 h; unsigned short u; } ua, ub;
  ua.h = (bf16)a; ub.h = (bf16)b;
  return ((unsigned)ub.u << 16) | (unsigned)ua.u;
}

// max of 4 via chain (folds to v_max3 + v_max)
static __device__ inline float max4(float a, float b, float c, float d) {
  return fmaxf(fmaxf(fmaxf(a, b), c), d);
}

// ---------------------------------------------------------------------------
// prep: W [1024][128] f32 (in,out)  ->  WT [128][1024] bf16  (out-major)
// ---------------------------------------------------------------------------
__global__ __launch_bounds__(256) void wt_prep(const float* __restrict__ Wq,
                                               const float* __restrict__ Wk,
                                               const float* __restrict__ Wv,
                                               bf16* __restrict__ WT) {
  const int mode = blockIdx.y;
  const float* W = (mode == 0) ? Wq : (mode == 1) ? Wk : Wv;
  const int idx = blockIdx.x * 256 + threadIdx.x;  // 0..131071 over [128][1024]
  const int n = idx >> 10;                         // head dim 0..127
  const int k = idx & 1023;                        // in dim  0..1023
  WT[(size_t)mode * 131072 + idx] = (bf16)W[(size_t)k * HDIM + n];
}

// ---------------------------------------------------------------------------
// QKV GEMM (R10/R14-verified): C[16384,128] = x (f32->bf16) @ W per mode.
// 128x128 tile, BK=32, 4 waves (2x2 of 64x64), mfma_f32_16x16x32_bf16.
// A and B reg-prefetched one K-step ahead (latency hidden under compute).
// mode 0: qb scaled 1/32; mode 1: kb; mode 2: vTc[key>>6][d][key&63] pre-tiled.
// ---------------------------------------------------------------------------
__global__ __launch_bounds__(256) void qkv_gemm(const float* __restrict__ x,
                                                const bf16* __restrict__ WT,
                                                bf16* __restrict__ qb,
                                                bf16* __restrict__ kb,
                                                bf16* __restrict__ vT) {
  __shared__ __attribute__((aligned(16))) bf16 a_tile[128 * 32];
  __shared__ __attribute__((aligned(16))) bf16 b_tile[128 * 32];
  const int tid = threadIdx.x;
  const int wid = tid >> 6;
  const int lane = tid & 63;
  const int lr = lane & 15;
  const int lg = lane >> 4;
  const int wr = wid >> 1;  // 0..1 row block of 64
  const int wc = wid & 1;   // 0..1 col block of 64
  const int mode = blockIdx.y;
  const int m0 = blockIdx.x * 128;
  const bf16* wt = WT + (size_t)mode * 131072;

  int rowA[2], col8[2];
#pragma unroll
  for (int g = 0; g < 2; ++g) {
    const int idx8 = g * 256 + tid;
    rowA[g] = idx8 >> 2;
    col8[g] = (idx8 & 3) * 8;
  }

  f32x4 acc[4][4] = {};

  float4 fA[2][2];
  bf16x8 fB[2];
#pragma unroll
  for (int g = 0; g < 2; ++g) {  // prefetch kt = 0
    const float* src = x + (size_t)(m0 + rowA[g]) * CDIM + col8[g];
    fA[g][0] = *(const float4*)src;
    fA[g][1] = *(const float4*)(src + 4);
    fB[g] = *(const bf16x8*)(wt + (size_t)rowA[g] * CDIM + col8[g]);
  }

#pragma unroll 1
  for (int kt = 0; kt < 32; ++kt) {
    __syncthreads();  // prior iteration's fragment reads done
#pragma unroll
    for (int g = 0; g < 2; ++g) {
      bf16x8 av;
      av[0] = (bf16)fA[g][0].x; av[1] = (bf16)fA[g][0].y;
      av[2] = (bf16)fA[g][0].z; av[3] = (bf16)fA[g][0].w;
      av[4] = (bf16)fA[g][1].x; av[5] = (bf16)fA[g][1].y;
      av[6] = (bf16)fA[g][1].z; av[7] = (bf16)fA[g][1].w;
      *(bf16x8*)&a_tile[rowA[g] * 32 + col8[g]] = av;
      *(bf16x8*)&b_tile[rowA[g] * 32 + col8[g]] = fB[g];
    }
    __syncthreads();  // tiles staged
    if (kt + 1 < 32) {
#pragma unroll
      for (int g = 0; g < 2; ++g) {
        const float* src = x + (size_t)(m0 + rowA[g]) * CDIM + (kt + 1) * 32 + col8[g];
        fA[g][0] = *(const float4*)src;
        fA[g][1] = *(const float4*)(src + 4);
        fB[g] = *(const bf16x8*)(wt + (size_t)rowA[g] * CDIM + (kt + 1) * 32 + col8[g]);
      }
    }
    bf16x8 af[4], bfr[4];
#pragma unroll
    for (int r = 0; r < 4; ++r)
      af[r] = *(const bf16x8*)&a_tile[(wr * 64 + r * 16 + lr) * 32 + lg * 8];
#pragma unroll
    for (int c = 0; c < 4; ++c)
      bfr[c] = *(const bf16x8*)&b_tile[(wc * 64 + c * 16 + lr) * 32 + lg * 8];
#pragma unroll
    for (int r = 0; r < 4; ++r)
#pragma unroll
      for (int c = 0; c < 4; ++c)
        acc[r][c] = __builtin_amdgcn_mfma_f32_16x16x32_bf16(af[r], bfr[c], acc[r][c], 0, 0, 0);
  }

  if (mode < 2) {
    bf16* dst = (mode == 0) ? qb : kb;
    const float sc = (mode == 0) ? 0.03125f : 1.0f;  // fold C^-0.5 into q (exact)
#pragma unroll
    for (int r = 0; r < 4; ++r)
#pragma unroll
      for (int c = 0; c < 4; ++c)
#pragma unroll
        for (int j = 0; j < 4; ++j) {
          const int row = m0 + wr * 64 + r * 16 + lg * 4 + j;
          const int col = wc * 64 + c * 16 + lr;
          dst[(size_t)row * HDIM + col] = (bf16)(acc[r][c][j] * sc);
        }
  } else {
    // v pre-tiled: vTc[key>>6][d][key&63]; 16KB per 64-key block (contiguous)
#pragma unroll
    for (int r = 0; r < 4; ++r)
#pragma unroll
      for (int c = 0; c < 4; ++c) {
        const int row0 = m0 + wr * 64 + r * 16 + lg * 4;  // key index (4-aligned)
        const int col = wc * 64 + c * 16 + lr;            // d
        bf16x4 pv;
        pv[0] = (bf16)acc[r][c][0]; pv[1] = (bf16)acc[r][c][1];
        pv[2] = (bf16)acc[r][c][2]; pv[3] = (bf16)acc[r][c][3];
        *(bf16x4*)(vT + (size_t)(row0 >> 6) * 8192 + col * 64 + (row0 & 63)) = pv;
      }
  }
}

// ---------------------------------------------------------------------------
// Flash attention phase 1 (split-KV, block-cooperative, swapped QK^T) — R14
// verified. Block = 8 waves x 16 q-rows = 128 rows over one KV chunk. K tile
// (64x128) and V tile (128x64, pre-tiled vTc) staged in LDS, dbuf, via
// global_load_lds with pre-swizzled source (col ^= (row&7)<<4). S^T = mfma(K,Q):
// softmax in-lane; gated defer-max; lane-local l_. 80 KB LDS -> 2 blocks/CU.
// XCD chunk-affinity (maxc==8): XCD j runs chunks {(c=j,b=0,1),(c=7-j,b=2,3)}.
// ---------------------------------------------------------------------------
__global__ __launch_bounds__(512, 4) void attn_part(const bf16* __restrict__ qg,
                                                    const bf16* __restrict__ kb,
                                                    const bf16* __restrict__ vT,
                                                    bf16* __restrict__ po,
                                                    float* __restrict__ pm,
                                                    float* __restrict__ pl,
                                                    int cshift, int maxc) {
  // [2 buffers][K 16KB | V 16KB] + P 16KB = 80 KB
  __shared__ __attribute__((aligned(16))) char kv_lds[2][32768];
  __shared__ __attribute__((aligned(16))) bf16 p_lds[8][16][64];
  const int tid = threadIdx.x;
  const int wid = tid >> 6;       // 0..7
  const int lane = tid & 63;
  const int lr = lane & 15;
  const int lg = lane >> 4;

  // ---- XCD chunk-affinity remap (maxc==8 tier only) ----
  int bx = blockIdx.x, c = blockIdx.y, b = blockIdx.z;
  if (maxc == 8) {
    const int p = blockIdx.x + 32 * (blockIdx.y + 8 * blockIdx.z);
    const int xcd = p & 7;
    const int s = p >> 3;        // 0..127 within XCD
    const int combo = s >> 5;    // 0..3
    bx = s & 31;
    b = combo;
    c = (combo < 2) ? xcd : 7 - xcd;
  }

  const int qbase = bx * 128;
  const int kv0 = c << cshift;
  if (kv0 >= qbase + 128) return;  // block-uniform early exit
  const int kvend = min(kv0 + (1 << cshift), qbase + 128);  // 64-multiples
  const int nt = (kvend - kv0) >> 6;
  const int qr0 = qbase + wid * 16;
  const int grp = bx * 8 + wid;  // 0..255
  const size_t qrow = (size_t)b * TSEQ + qr0;

  // ---- staging source byte offsets (source pre-swizzled, dest linear) ----
  const int wbase = wid * 2048;  // each wave stages 2KB of K and 2KB of V
  int ksrc[2], vsrc[2];
#pragma unroll
  for (int i = 0; i < 2; ++i) {
    const int o = wbase + i * 1024 + lane * 16;  // linear dest byte in tile
    const int rk = o >> 8;                       // K row (256B rows)
    ksrc[i] = rk * 256 + ((o & 255) ^ ((rk & 7) << 4));
    const int rv = o >> 7;                       // V d-row (128B rows, contiguous tile)
    vsrc[i] = rv * 128 + ((o & 127) ^ ((rv & 7) << 4));
  }
  const char* kgb = (const char*)kb + (size_t)b * TSEQ * 256;  // + key*256B
  const char* vgb = (const char*)vT + (size_t)b * TSEQ * 256;  // + key*256B (tiled)

  // ---- fragment read bases (XOR split over disjoint bit fields) ----
  const int msk = (lr & 7) << 4;  // full mask bits 4-6
  const int m30 = (lr & 3) << 4;  // mask bits 4-5
  const int m6 = (lr & 4) << 4;   // mask bit 6
  const int lgx = (lg * 16) ^ m30;
  const int kreadA = lr * 256 + lgx + m6;         // d even (+128 for d=2)
  const int kreadB = lr * 256 + lgx + (64 ^ m6);  // d odd  (+128 for d=3)
  const int vreadA = 16384 + lr * 128 + lgx + m6;         // ks=0
  const int vreadB = 16384 + lr * 128 + lgx + (64 ^ m6);  // ks=1

  // Q fragments (hoisted): B-operand layout
  bf16x8 qf[4];
#pragma unroll
  for (int d = 0; d < 4; ++d)
    qf[d] = *(const bf16x8*)(qg + (qrow + lr) * HDIM + d * 32 + lg * 8);

  f32x4 o_[8] = {};              // O^T: o_[o][j] = O[q=lr][d = 16o + 4lg + j]
  float m_ = -1e30f, l_ = 0.0f;  // m_: row-uniform running max; l_: LANE-LOCAL

  // ---- prologue: stage tile 0 into buffer 0 ----
  {
    const char* ks = kgb + (size_t)kv0 * 256;
    const char* vs = vgb + (size_t)kv0 * 256;
#pragma unroll
    for (int i = 0; i < 2; ++i) {
      GLDS(ks + ksrc[i], &kv_lds[0][wbase + i * 1024]);
      GLDS(vs + vsrc[i], &kv_lds[0][16384 + wbase + i * 1024]);
    }
  }
  __syncthreads();  // drains vmcnt: tile 0 resident

  int cur = 0;
  for (int t = 0; t < nt; ++t) {
    const int kvt = kv0 + (t << 6);
    // ---- issue next tile's staging (flies under compute) ----
    if (t + 1 < nt) {
      const char* ks = kgb + (size_t)(kvt + 64) * 256;
      const char* vs = vgb + (size_t)(kvt + 64) * 256;
#pragma unroll
      for (int i = 0; i < 2; ++i) {
        GLDS(ks + ksrc[i], &kv_lds[cur ^ 1][wbase + i * 1024]);
        GLDS(vs + vsrc[i], &kv_lds[cur ^ 1][16384 + wbase + i * 1024]);
      }
    }
    // ---- compute (waves whose rows end before this tile just barrier) ----
    if (kvt < qr0 + 16) {
      const char* kbuf = kv_lds[cur];
      // S^T = mfma(A=K, B=Q): s[nf][j] = S[q=lr][key = kvt + nf*16 + lg*4 + j]
      f32x4 s[4] = {};
      __builtin_amdgcn_s_setprio(1);
#pragma unroll
      for (int nf = 0; nf < 4; ++nf) {
        const char* kb0 = kbuf + nf * 4096;
        bf16x8 kf;
        kf = *(const bf16x8*)(kb0 + kreadA);
        s[nf] = __builtin_amdgcn_mfma_f32_16x16x32_bf16(kf, qf[0], s[nf], 0, 0, 0);
        kf = *(const bf16x8*)(kb0 + kreadB);
        s[nf] = __builtin_amdgcn_mfma_f32_16x16x32_bf16(kf, qf[1], s[nf], 0, 0, 0);
        kf = *(const bf16x8*)(kb0 + kreadA + 128);
        s[nf] = __builtin_amdgcn_mfma_f32_16x16x32_bf16(kf, qf[2], s[nf], 0, 0, 0);
        kf = *(const bf16x8*)(kb0 + kreadB + 128);
        s[nf] = __builtin_amdgcn_mfma_f32_16x16x32_bf16(kf, qf[3], s[nf], 0, 0, 0);
      }
      __builtin_amdgcn_s_setprio(0);
      // causal mask (only tiles crossing the diagonal)
      if (kvt + 63 >= qr0) {
        const int q = qr0 + lr;
#pragma unroll
        for (int nf = 0; nf < 4; ++nf)
#pragma unroll
          for (int j = 0; j < 4; ++j)
            if (kvt + nf * 16 + lg * 4 + j > q) s[nf][j] = -1e30f;
      }
      // lane-local row max (max3-friendly chains)
      float r0 = max4(s[0][0], s[0][1], s[0][2], s[0][3]);
      float r1 = max4(s[1][0], s[1][1], s[1][2], s[1][3]);
      float r2 = max4(s[2][0], s[2][1], s[2][2], s[2][3]);
      float r3 = max4(s[3][0], s[3][1], s[3][2], s[3][3]);
      const float rloc = max4(r0, r1, r2, r3);
      // gated defer-max: cross-lane reduce + rescale only when needed
      if (!__all(rloc <= m_ + 8.0f)) {
        float rmax = fmaxf(rloc, __shfl_xor(rloc, 16));
        rmax = fmaxf(rmax, __shfl_xor(rmax, 32));
        const float mn = fmaxf(m_, rmax);
        const float al = exp2f((m_ - mn) * L2E);
        m_ = mn;
        l_ *= al;
#pragma unroll
        for (int o = 0; o < 8; ++o)
#pragma unroll
          for (int j = 0; j < 4; ++j) o_[o][j] *= al;
      }
      float rsum = 0.0f;
#pragma unroll
      for (int nf = 0; nf < 4; ++nf)
#pragma unroll
        for (int j = 0; j < 4; ++j) {
          s[nf][j] = exp2f((s[nf][j] - m_) * L2E);
          rsum += s[nf][j];
        }
      l_ += rsum;  // lane-local; cross-lane reduced once at the end
      // P^T -> swizzled p_lds [q-row][key], one b64 write per nf
      {
        char* pw = (char*)p_lds + wid * 2048 + lr * 128;
#pragma unroll
        for (int nf = 0; nf < 4; ++nf) {
          uint2 w2;
          w2.x = pkbf(s[nf][0], s[nf][1]); w2.y = pkbf(s[nf][2], s[nf][3]);
          *(uint2*)(pw + (((nf * 32) + lg * 8) ^ msk)) = w2;
        }
      }
      asm volatile("s_waitcnt lgkmcnt(0)" ::: "memory");
      __builtin_amdgcn_sched_barrier(0);  // keep dependent MFMAs below the wait
      // O^T += V^T P^T  (A = V^T frag; B = P^T frag, swizzled read)
      const char* pr = (const char*)p_lds + wid * 2048 + lr * 128;
      bf16x8 pf0 = *(const bf16x8*)(pr + lgx + m6);
      bf16x8 pf1 = *(const bf16x8*)(pr + lgx + (64 ^ m6));
      __builtin_amdgcn_s_setprio(1);
#pragma unroll
      for (int o = 0; o < 8; ++o) {
        bf16x8 vf;
        vf = *(const bf16x8*)(kbuf + vreadA + o * 2048);
        o_[o] = __builtin_amdgcn_mfma_f32_16x16x32_bf16(vf, pf0, o_[o], 0, 0, 0);
        vf = *(const bf16x8*)(kbuf + vreadB + o * 2048);
        o_[o] = __builtin_amdgcn_mfma_f32_16x16x32_bf16(vf, pf1, o_[o], 0, 0, 0);
      }
      __builtin_amdgcn_s_setprio(0);
    }
    __syncthreads();  // staging (vmcnt) drained; everyone done with buf[cur]
    cur ^= 1;
  }

  // ---- finalize lane-local l_ (one cross-lane reduce per kernel) ----
  l_ += __shfl_xor(l_, 16);
  l_ += __shfl_xor(l_, 32);

  // ---- write unnormalized partials: lane owns q-row lr ----
  const size_t slot = (size_t)(b * 256 + grp) * maxc + c;
  bf16* pob = po + slot * (16 * HDIM);
#pragma unroll
  for (int o = 0; o < 8; ++o) {
    bf16x4 pv;
    pv[0] = (bf16)o_[o][0]; pv[1] = (bf16)o_[o][1];
    pv[2] = (bf16)o_[o][2]; pv[3] = (bf16)o_[o][3];
    *(bf16x4*)(pob + lr * HDIM + o * 16 + lg * 4) = pv;
  }
  if (lg == 0) {
    pm[slot * 16 + lr] = m_;
    pl[slot * 16 + lr] = l_;
  }
}

// ---------------------------------------------------------------------------
// Flash attention phase 2: merge <=maxc partials per (batch, group).
// ---------------------------------------------------------------------------
__global__ __launch_bounds__(256) void attn_merge(const bf16* __restrict__ po,
                                                  const float* __restrict__ pm,
                                                  const float* __restrict__ pl,
                                                  float* __restrict__ out,
                                                  int cshift, int maxc) {
  const int bg = blockIdx.x;          // b*256 + g
  const int g = bg & 255;
  const int nch = ((g << 4) >> cshift) + 1;
  const int row = threadIdx.x >> 4;
  const int d8 = (threadIdx.x & 15) * 8;
  const size_t slot0 = (size_t)bg * maxc;

  float M = -1e30f;
  for (int c = 0; c < nch; ++c) M = fmaxf(M, pm[(slot0 + c) * 16 + row]);
  float L = 0.0f;
  float acc[8] = {};
  for (int c = 0; c < nch; ++c) {
    const float w = exp2f((pm[(slot0 + c) * 16 + row] - M) * L2E);
    L += w * pl[(slot0 + c) * 16 + row];
    const bf16x8 v = *(const bf16x8*)(po + (slot0 + c) * (16 * HDIM) + row * HDIM + d8);
#pragma unroll
    for (int i = 0; i < 8; ++i) acc[i] += w * (float)v[i];
  }
  const float inv = 1.0f / L;
  f32x4 r0, r1;
#pragma unroll
  for (int i = 0; i < 4; ++i) { r0[i] = acc[i] * inv; r1[i] = acc[i + 4] * inv; }
  float* dst = out + (size_t)bg * (16 * HDIM) + row * HDIM + d8;
  *(f32x4*)dst = r0;
  *(f32x4*)(dst + 4) = r1;
}

// ---------------------------------------------------------------------------
extern "C" void kernel_launch(void* const* d_in, const int* in_sizes, int n_in,
                              void* d_out, int out_size, void* d_ws, size_t ws_size,
                              hipStream_t stream) {
  const float* x  = (const float*)d_in[0];
  const float* Wk = (const float*)d_in[1];
  const float* Wq = (const float*)d_in[2];
  const float* Wv = (const float*)d_in[3];
  float* out = (float*)d_out;

  char* ws = (char*)d_ws;
  bf16* qb = (bf16*)(ws);                   // [16384][128] bf16, 4 MB
  bf16* kb = (bf16*)(ws + 4194304);         // [16384][128] bf16, 4 MB
  bf16* vT = (bf16*)(ws + 8388608);         // vTc[256][128][64] bf16, 4 MB
  bf16* WT = (bf16*)(ws + 12582912);        // [3][128][1024] bf16, 768 KB
  const size_t pbase = 13369344;

  // choose KV-chunking tier by available workspace:
  //   per-slot bytes: 16*128*2 (po) + 2*16*4 (pm,pl) = 4224; slots = 1024*maxc
  int cshift, maxc;
  if (ws_size >= pbase + 8ull * 1024 * 4224) { cshift = 9;  maxc = 8; }       // 512-key chunks
  else if (ws_size >= pbase + 4ull * 1024 * 4224) { cshift = 10; maxc = 4; }  // 1024-key
  else { cshift = 12; maxc = 1; }                                             // no split
  bf16* po = (bf16*)(ws + pbase);
  float* pm = (float*)(ws + pbase + (size_t)maxc * 1024 * 16 * 128 * 2);
  float* pl = pm + (size_t)maxc * 1024 * 16;

  wt_prep<<<dim3(512, 3), 256, 0, stream>>>(Wq, Wk, Wv, WT);
  qkv_gemm<<<dim3(128, 3), 256, 0, stream>>>(x, WT, qb, kb, vT);
  attn_part<<<dim3(32, maxc, 4), 512, 0, stream>>>(qb, kb, vT, po, pm, pl, cshift, maxc);
  attn_merge<<<1024, 256, 0, stream>>>(po, pm, pl, out, cshift, maxc);
}